// Round 3
// baseline (712.467 us; speedup 1.0000x reference)
//
#include <hip/hip_runtime.h>
#include <hip/hip_bf16.h>

// Problem constants
#define B_   8
#define CIN  64
#define CM   16      // compressed channels
#define H_   192
#define W_   384
#define ND   41      // MAX_DISP+1
#define HW   (H_ * W_)
#define SLOPE 0.1f
#define SMINI ((size_t)B_ * CM * H_ * W_)   // elems per compressed tensor

typedef __attribute__((ext_vector_type(8))) short short8v;
typedef __attribute__((ext_vector_type(4))) float floatx4;

__device__ __forceinline__ float bf2f(short h) {
    union { unsigned u; float f; } cv;
    cv.u = ((unsigned)(unsigned short)h) << 16;
    return cv.f;
}
__device__ __forceinline__ short f2bf(float f) {
    __hip_bfloat16 h = __float2bfloat16(f);   // RNE
    return *(short*)&h;
}

// ---------------------------------------------------------------------------
// Kernel 0: weights OIHW fp32 -> lane-ordered bf16 A-frags.
// wbf2[ks][lane][u]: ks=0..17 (tap,ch-half), lane=(quad<<4)|n16, u=0..7.
// A-frag element: co=n16 (M), k-local = quad*8+u -> c=(ks&1)*32+quad*8+u,
// tap = ks>>1. One wave reads 1024 contiguous bytes per ks.
// ---------------------------------------------------------------------------
__global__ void wprep_kernel(const float* __restrict__ w, short* __restrict__ wbf2) {
    int i = blockIdx.x * 256 + threadIdx.x;
    if (i >= 18 * 512) return;
    int ks = i >> 9;          // 0..17
    int r  = i & 511;
    int n16  = r >> 5;        // 0..15  (co)
    int quad = (r >> 3) & 3;  // 0..3
    int u    = r & 7;         // 0..7
    int c   = (ks & 1) * 32 + quad * 8 + u;
    int tap = ks >> 1;        // dy*3+dx
    // memory order must be: offset = ks*512 + (quad*16 + n16)*8 + u
    int o = ks * 512 + (quad * 16 + n16) * 8 + u;
    wbf2[o] = f2bf(w[(n16 * CIN + c) * 9 + tap]);
}

// ---------------------------------------------------------------------------
// Kernel 1: 3x3 conv 64->16 + bias + LeakyReLU, MFMA, NO LDS.
// B-frags loaded directly from NCHW fp32 global (8 ch-strided dwords, lanes
// coalesced along x); L1 absorbs the 9x tap re-reads (13.8 KB/M-tile slab).
// Block = (t,b, 6-row x 32-col tile), 4 waves x 3 M-tiles.
// XCD swizzle: blockIdx%8 -> XCD, so each XCD works a contiguous 2-image band.
// ---------------------------------------------------------------------------
__global__ __launch_bounds__(256, 4) void conv_direct(
    const float* __restrict__ ina, const float* __restrict__ inb,
    const short* __restrict__ wbf2, const float* __restrict__ bias,
    short* __restrict__ mini)      // [2][B][H][W][16] bf16 NHWC
{
    // XCD-aware swizzle: hw round-robins blockIdx%8 across XCDs
    int blk = (blockIdx.x & 7) * 768 + (blockIdx.x >> 3);
    int xt = blk % 12;  blk /= 12;
    int yt = blk % 32;  blk /= 32;
    int b  = blk & 7;
    int t  = blk >> 3;
    const float* src = t ? inb : ina;
    int x0 = xt * 32, y0 = yt * 6;
    int tid = threadIdx.x;
    int lane = tid & 63, wv = tid >> 6;
    int n16 = lane & 15, quad = lane >> 4;

    const float* sb = src + (size_t)b * CIN * HW;

    floatx4 acc[3] = {{0,0,0,0},{0,0,0,0},{0,0,0,0}};
    int rs[3], xs[3];
    #pragma unroll
    for (int j = 0; j < 3; ++j) {
        int mt = wv * 3 + j;               // 0..11
        rs[j] = mt >> 1;                   // row 0..5
        xs[j] = x0 + ((mt & 1) << 4) + n16;
    }

    #pragma unroll
    for (int ks = 0; ks < 18; ++ks) {
        const int tap = ks >> 1, h = ks & 1;
        const int dy = tap / 3, dx = tap % 3;
        const int cbase = h * 32 + quad * 8;
        short8v af = *(const short8v*)(wbf2 + ks * 512 + lane * 8);  // L1-hot
        const float* cb = sb + (size_t)cbase * HW;
        #pragma unroll
        for (int j = 0; j < 3; ++j) {
            int yy = y0 + rs[j] + dy - 1;                 // wave-uniform
            if ((unsigned)yy < (unsigned)H_) {
                int xx = xs[j] + dx - 1;                  // per-lane
                bool ok = (unsigned)xx < (unsigned)W_;
                int xxc = ok ? xx : 0;
                const float* p = cb + (size_t)yy * W_ + xxc;
                float v[8];
                #pragma unroll
                for (int u = 0; u < 8; ++u) v[u] = p[(size_t)u * HW];
                short8v bfr;
                #pragma unroll
                for (int u = 0; u < 8; ++u) bfr[u] = f2bf(ok ? v[u] : 0.f);
                acc[j] = __builtin_amdgcn_mfma_f32_16x16x32_bf16(af, bfr, acc[j], 0, 0, 0);
            }
        }
    }

    // epilogue: bias + LeakyReLU, bf16 NHWC store (8 B/lane, coalesced)
    float bia[4];
    #pragma unroll
    for (int i = 0; i < 4; ++i) bia[i] = bias[quad * 4 + i];
    #pragma unroll
    for (int j = 0; j < 3; ++j) {
        int mt = wv * 3 + j;
        int r = mt >> 1, xb = (mt & 1) << 4;
        int y = y0 + r, x = x0 + xb + n16;
        size_t o = (((size_t)(t * B_ + b) * H_ + y) * W_ + x) * CM + quad * 4;
        short4 q;
        float v;
        v = acc[j][0] + bia[0]; v = v >= 0.f ? v : SLOPE * v; q.x = f2bf(v);
        v = acc[j][1] + bia[1]; v = v >= 0.f ? v : SLOPE * v; q.y = f2bf(v);
        v = acc[j][2] + bia[2]; v = v >= 0.f ? v : SLOPE * v; q.z = f2bf(v);
        v = acc[j][3] + bia[3]; v = v >= 0.f ? v : SLOPE * v; q.w = f2bf(v);
        *(short4*)(mini + o) = q;
    }
}

// ---------------------------------------------------------------------------
// Kernel 2: 41-disparity correlation. One block per (b,y) row.
// b-row in LDS as fp32, 20-float (80 B) pixel stride: lane b128 reads land on
// quad-bank (5*x+q)%8 -- a permutation -> conflict-free. cvts hoisted out of
// the d-loop; inner loop = 4x ds_read_b128 + 16 v_fma + 1 coalesced store.
// ---------------------------------------------------------------------------
#define CST 20
__global__ __launch_bounds__(384) void corr_f32(
    const short* __restrict__ mini, float* __restrict__ out)
{
    __shared__ __align__(16) float bl[W_ * CST];   // 30,720 B
    int b = blockIdx.x / H_;
    int y = blockIdx.x % H_;
    int x = threadIdx.x;   // 0..383

    size_t arow = ((size_t)b * H_ + y) * (size_t)W_ * CM;
    size_t brow = ((size_t)(B_ + b) * H_ + y) * (size_t)W_ * CM;

    short8v p0 = *(const short8v*)(mini + brow + (size_t)x * CM);
    short8v p1 = *(const short8v*)(mini + brow + (size_t)x * CM + 8);
    float* bw = bl + x * CST;
    #pragma unroll
    for (int i = 0; i < 8; ++i) { bw[i] = bf2f(p0[i]); bw[8 + i] = bf2f(p1[i]); }

    float av[16];
    short8v a0 = *(const short8v*)(mini + arow + (size_t)x * CM);
    short8v a1 = *(const short8v*)(mini + arow + (size_t)x * CM + 8);
    #pragma unroll
    for (int i = 0; i < 8; ++i) { av[i] = bf2f(a0[i]); av[8 + i] = bf2f(a1[i]); }

    __syncthreads();

    float* ob = out + ((size_t)b * ND * H_ + y) * W_ + x;
    #pragma unroll 1
    for (int d = 0; d < ND; ++d) {
        float s = 0.f;
        int xs = x - d;
        if (xs >= 0) {
            const float4* bp = (const float4*)(bl + xs * CST);
            float4 b0 = bp[0], b1 = bp[1], b2 = bp[2], b3 = bp[3];
            s  = av[0]  * b0.x + av[1]  * b0.y + av[2]  * b0.z + av[3]  * b0.w;
            s += av[4]  * b1.x + av[5]  * b1.y + av[6]  * b1.z + av[7]  * b1.w;
            s += av[8]  * b2.x + av[9]  * b2.y + av[10] * b2.z + av[11] * b2.w;
            s += av[12] * b3.x + av[13] * b3.y + av[14] * b3.z + av[15] * b3.w;
        }
        ob[(size_t)d * HW] = s * 0.0625f;
    }
}

// ---------------------------------------------------------------------------
extern "C" void kernel_launch(void* const* d_in, const int* in_sizes, int n_in,
                              void* d_out, int out_size, void* d_ws, size_t ws_size,
                              hipStream_t stream) {
    const float* conv1a = (const float*)d_in[0];
    const float* conv1b = (const float*)d_in[1];
    const float* W_comp = (const float*)d_in[2];
    const float* b_comp = (const float*)d_in[3];
    float* out = (float*)d_out;

    short* mini = (short*)d_ws;            // 2*SMINI bf16 = 37.7 MB
    short* wbf2 = mini + 2 * SMINI;        // 18*512 bf16 lane-ordered frags

    wprep_kernel<<<36, 256, 0, stream>>>(W_comp, wbf2);
    conv_direct<<<2 * B_ * 32 * 12, 256, 0, stream>>>(conv1a, conv1b, wbf2, b_comp, mini);
    corr_f32<<<B_ * H_, 384, 0, stream>>>(mini, out);
}